// Round 1
// baseline (322.804 us; speedup 1.0000x reference)
//
#include <hip/hip_runtime.h>
#include <cstdint>
#include <cstddef>

#define BETA 5.5f
#define ALPHA 0.5f

constexpr int D   = 512;     // feature dim
constexpr int NB  = 4096;    // queries
constexpr int NK  = 16384;   // keys
constexpr int BQ  = 64;      // query tile per block
constexpr int BN  = 64;      // key chunk
constexpr int NSPLIT = 4;
constexpr int NRANGE = NK / NSPLIT;   // 4096
constexpr int CHUNKS = NRANGE / BN;   // 64
constexpr int KROW = D + 8;           // padded LDS row (bf16), 1040 B
constexpr int PROW = BN + 8;          // padded P row: 72

typedef __attribute__((ext_vector_type(8)))  short    short8;
typedef __attribute__((ext_vector_type(4)))  float    floatx4;
typedef __attribute__((ext_vector_type(4)))  uint32_t uint4v;
typedef __attribute__((ext_vector_type(2)))  uint32_t uint2v;

__device__ inline uint32_t f2bf1(float f) {
  union { float f; uint32_t u; } v; v.f = f;
  return (v.u + 0x7FFFu + ((v.u >> 16) & 1u)) >> 16;   // RNE
}
__device__ inline uint32_t pack2(float a, float b) {
  return f2bf1(a) | (f2bf1(b) << 16);
}

__device__ inline void load_lds16(const void* g, void* l) {
  __builtin_amdgcn_global_load_lds(
      (const __attribute__((address_space(1))) uint32_t*)g,
      (__attribute__((address_space(3))) uint32_t*)l, 16, 0, 0);
}

// ---------------- normalize Q -> Qn (bf16), and init out = Q ----------------
__global__ void norm_q_kernel(const float* __restrict__ q,
                              float* __restrict__ out,
                              unsigned short* __restrict__ Qn) {
  const int wave = threadIdx.x >> 6, lane = threadIdx.x & 63;
  const int row = blockIdx.x * 4 + wave;
  const float4* qr = (const float4*)(q + (size_t)row * D);
  float4 a = qr[lane * 2];
  float4 b = qr[lane * 2 + 1];
  float ss = a.x*a.x + a.y*a.y + a.z*a.z + a.w*a.w
           + b.x*b.x + b.y*b.y + b.z*b.z + b.w*b.w;
#pragma unroll
  for (int m = 32; m >= 1; m >>= 1) ss += __shfl_xor(ss, m, 64);
  const float sc = 1.0f / fmaxf(sqrtf(ss), 1e-12f);
  float4* orow = (float4*)(out + (size_t)row * D);
  orow[lane * 2]     = a;
  orow[lane * 2 + 1] = b;
  uint4v w;
  w.x = pack2(a.x*sc, a.y*sc); w.y = pack2(a.z*sc, a.w*sc);
  w.z = pack2(b.x*sc, b.y*sc); w.w = pack2(b.z*sc, b.w*sc);
  *(uint4v*)(Qn + (size_t)row * D + lane * 8) = w;
}

// ------ normalize K -> Kn (bf16 row-major) + KnT (bf16 transposed) ----------
__global__ void norm_k_kernel(const float* __restrict__ k,
                              unsigned short* __restrict__ Kn,
                              unsigned short* __restrict__ KnT) {
  __shared__ unsigned short tile[64 * KROW];
  const int wave = threadIdx.x >> 6, lane = threadIdx.x & 63;
  const int n0 = blockIdx.x * 64;
#pragma unroll
  for (int i = 0; i < 4; ++i) {
    const int rl = wave * 4 + i;
    const int n  = n0 + rl;
    const float4* kr = (const float4*)(k + (size_t)n * D);
    float4 a = kr[lane * 2], b = kr[lane * 2 + 1];
    float ss = a.x*a.x + a.y*a.y + a.z*a.z + a.w*a.w
             + b.x*b.x + b.y*b.y + b.z*b.z + b.w*b.w;
#pragma unroll
    for (int m = 32; m >= 1; m >>= 1) ss += __shfl_xor(ss, m, 64);
    const float sc = 1.0f / fmaxf(sqrtf(ss), 1e-12f);
    uint4v w;
    w.x = pack2(a.x*sc, a.y*sc); w.y = pack2(a.z*sc, a.w*sc);
    w.z = pack2(b.x*sc, b.y*sc); w.w = pack2(b.z*sc, b.w*sc);
    *(uint4v*)(Kn + (size_t)n * D + lane * 8) = w;
    *(uint4v*)&tile[rl * KROW + lane * 8]     = w;
  }
  __syncthreads();
  const int dsub = threadIdx.x >> 3;        // 0..127
  const int nl   = (threadIdx.x & 7) * 8;   // 0..56
#pragma unroll
  for (int iter = 0; iter < 4; ++iter) {
    const int d = iter * 128 + dsub;
    uint4v w;
    w.x = (uint32_t)tile[(nl+0)*KROW + d] | ((uint32_t)tile[(nl+1)*KROW + d] << 16);
    w.y = (uint32_t)tile[(nl+2)*KROW + d] | ((uint32_t)tile[(nl+3)*KROW + d] << 16);
    w.z = (uint32_t)tile[(nl+4)*KROW + d] | ((uint32_t)tile[(nl+5)*KROW + d] << 16);
    w.w = (uint32_t)tile[(nl+6)*KROW + d] | ((uint32_t)tile[(nl+7)*KROW + d] << 16);
    *(uint4v*)(KnT + (size_t)d * NK + n0 + nl) = w;
  }
}

// ---------------- fused: S = Qn Kn^T chunk, P = exp, O += P Kn --------------
// Producer/consumer wave specialization:
//   waves 0-3 (S): GEMM1 32nx32q tiles, qf = 32q x 512k in regs (128 VGPR)
//                  -> each K_lds read feeds 2 MFMAs (was 1; 4x wave dup -> 2x)
//   waves 4-7 (O): GEMM2 64q x 128d slices, oacc 128 regs, ktf 64 regs
//                  -> P read by 4 waves (32 KB/chunk, was 64)
// Two separate loops with matched barrier counts (65 each) so qf and
// oacc/ktf have disjoint live ranges and share physical registers.
// Each SIMD hosts 1 S-wave + 1 O-wave: LDS-heavy and MFMA/global-heavy
// instruction streams overlap instead of convoying.
__global__ __launch_bounds__(512, 2) void fused_kernel(
    const unsigned short* __restrict__ Qn,
    const unsigned short* __restrict__ Kn,
    const unsigned short* __restrict__ KnT,
    float* __restrict__ out) {
  __shared__ unsigned short K_lds[2][BN * KROW];   // 2 x 66.5 KB
  __shared__ unsigned short P_lds[2][BQ * PROW];   // 2 x 9.2 KB  (151.5 KB)

  const int tid  = threadIdx.x;
  const int wave = tid >> 6, lane = tid & 63;
  const int l15  = lane & 15, quad = lane >> 4;
  const int nsplit = blockIdx.x & (NSPLIT - 1);
  const int qtile  = blockIdx.x >> 2;           // 0..63
  const int q0     = qtile * BQ;
  const int nbase  = nsplit * NRANGE;

  auto stage = [&](int ch, int buf) {
#pragma unroll
    for (int i = 0; i < 8; ++i) {
      const int row = wave * 8 + i;
      load_lds16(Kn + (size_t)(nbase + ch * BN + row) * D + lane * 8,
                 &K_lds[buf][row * KROW]);
    }
  };

  if (wave < 4) {
    // ================= S-producer: GEMM1 + exp -> P_lds ===================
    const int qh = wave & 1, nh = wave >> 1;
    // Q B-fragments: 32 q-cols (2 tiles) x all 512 k  -> 128 VGPR
    short8 qf[2][16];
    {
      const unsigned short* qrow0 = Qn + (size_t)(q0 + qh * 32 + l15) * D + quad * 8;
#pragma unroll
      for (int qt = 0; qt < 2; ++qt)
#pragma unroll
        for (int kb = 0; kb < 16; ++kb)
          qf[qt][kb] = *(const short8*)(qrow0 + (size_t)qt * 16 * D + kb * 32);
    }

    auto gemm1x = [&](int buf, int pbuf) {
      floatx4 sacc[2][2] = {};   // [nt][qt]
#pragma unroll
      for (int kb = 0; kb < 16; ++kb) {
        short8 a0 = *(const short8*)&K_lds[buf][(nh*32 +      l15) * KROW + kb*32 + quad*8];
        short8 a1 = *(const short8*)&K_lds[buf][(nh*32 + 16 + l15) * KROW + kb*32 + quad*8];
        sacc[0][0] = __builtin_amdgcn_mfma_f32_16x16x32_bf16(a0, qf[0][kb], sacc[0][0], 0, 0, 0);
        sacc[0][1] = __builtin_amdgcn_mfma_f32_16x16x32_bf16(a0, qf[1][kb], sacc[0][1], 0, 0, 0);
        sacc[1][0] = __builtin_amdgcn_mfma_f32_16x16x32_bf16(a1, qf[0][kb], sacc[1][0], 0, 0, 0);
        sacc[1][1] = __builtin_amdgcn_mfma_f32_16x16x32_bf16(a1, qf[1][kb], sacc[1][1], 0, 0, 0);
      }
#pragma unroll
      for (int qt = 0; qt < 2; ++qt)
#pragma unroll
        for (int nt = 0; nt < 2; ++nt) {
          const floatx4 s = sacc[nt][qt];
          uint2v w;
          w.x = pack2(__expf(BETA * (s[0] - 1.f)), __expf(BETA * (s[1] - 1.f)));
          w.y = pack2(__expf(BETA * (s[2] - 1.f)), __expf(BETA * (s[3] - 1.f)));
          *(uint2v*)&P_lds[pbuf][(qh*32 + qt*16 + l15) * PROW + nh*32 + nt*16 + quad*4] = w;
        }
    };

    stage(0, 0);
    __syncthreads();                       // B0: chunk 0 staged
    stage(1, 1);
    gemm1x(0, 0);                          // P(0) -> P_lds[0]
    __syncthreads();                       // B1

#pragma unroll 1
    for (int c = 0; c + 2 < CHUNKS; ++c) {
      const int cur = c & 1, nxt = cur ^ 1;
      stage(c + 2, cur);                   // K_lds[cur] free (chunk c consumed)
      gemm1x(nxt, nxt);                    // S(c+1) from K_lds[nxt] -> P_lds[nxt]
      __syncthreads();
    }
    // region CHUNKS-2: produce last P
    gemm1x((CHUNKS - 1) & 1, (CHUNKS - 1) & 1);
    __syncthreads();
    // S-waves done (O-waves still run final gemm2 — no more barriers needed)
  } else {
    // ================= O-consumer: GEMM2 + epilogue =======================
    const int w4 = wave - 4;               // 0..3 -> d-slice of 128
    floatx4 oacc[4][8] = {};               // 64q x 128d  (128 regs)
    short8 ktf[2][8];                      // 64 regs
    const unsigned short* ktbase = KnT + (size_t)(w4 * 128 + l15) * NK + nbase + quad * 8;

    auto ktf_half = [&](int ch, int kb2) {
#pragma unroll
      for (int td = 0; td < 8; ++td)
        ktf[kb2][td] = *(const short8*)(ktbase + (size_t)td * 16 * NK + ch * BN + kb2 * 32);
    };
    auto gemm2_half = [&](int pbuf, int kb2) {
      short8 pf[4];
#pragma unroll
      for (int tr = 0; tr < 4; ++tr)
        pf[tr] = *(const short8*)&P_lds[pbuf][(tr*16 + l15) * PROW + kb2*32 + quad*8];
#pragma unroll
      for (int td = 0; td < 8; ++td)
#pragma unroll
        for (int tr = 0; tr < 4; ++tr)
          oacc[tr][td] = __builtin_amdgcn_mfma_f32_16x16x32_bf16(
              pf[tr], ktf[kb2][td], oacc[tr][td], 0, 0, 0);
    };

    stage(0, 0);
    __syncthreads();                       // B0
    stage(1, 1);
    ktf_half(0, 0); ktf_half(0, 1);
    __syncthreads();                       // B1: P(0) visible

#pragma unroll 1
    for (int c = 0; c + 2 < CHUNKS; ++c) {
      const int cur = c & 1;
      stage(c + 2, cur);
      gemm2_half(cur, 0);                  // uses ktf[0] = chunk c
      ktf_half(c + 1, 0);                  // refill for chunk c+1
      gemm2_half(cur, 1);
      ktf_half(c + 1, 1);
      __syncthreads();
    }
    // region CHUNKS-2 (no staging left)
    {
      const int cur = (CHUNKS - 2) & 1;
      gemm2_half(cur, 0); ktf_half(CHUNKS - 1, 0);
      gemm2_half(cur, 1); ktf_half(CHUNKS - 1, 1);
      __syncthreads();
    }
    // final chunk
    {
      const int cur = (CHUNKS - 1) & 1;
      gemm2_half(cur, 0);
      gemm2_half(cur, 1);
    }

    // ---- epilogue: out += ALPHA * O (out pre-init to Q) ----
    const int colbase = w4 * 128 + l15;
#pragma unroll
    for (int tr = 0; tr < 4; ++tr)
#pragma unroll
      for (int td = 0; td < 8; ++td)
#pragma unroll
        for (int r = 0; r < 4; ++r)
          atomicAdd(out + (size_t)(q0 + tr*16 + quad*4 + r) * D + colbase + td*16,
                    ALPHA * oacc[tr][td][r]);
  }
}

extern "C" void kernel_launch(void* const* d_in, const int* in_sizes, int n_in,
                              void* d_out, int out_size, void* d_ws, size_t ws_size,
                              hipStream_t stream) {
  (void)in_sizes; (void)n_in; (void)out_size; (void)ws_size;
  const float* q = (const float*)d_in[0];
  const float* k = (const float*)d_in[1];
  float* out = (float*)d_out;
  unsigned short* Qn  = (unsigned short*)d_ws;          //  4 MB
  unsigned short* Kn  = Qn + (size_t)NB * D;            // 16 MB
  unsigned short* KnT = Kn + (size_t)NK * D;            // 16 MB  (total 36 MB)

  hipLaunchKernelGGL(norm_q_kernel, dim3(NB / 4),  dim3(256),  0, stream, q, out, Qn);
  hipLaunchKernelGGL(norm_k_kernel, dim3(NK / 64), dim3(1024), 0, stream, k, Kn, KnT);
  hipLaunchKernelGGL(fused_kernel, dim3((NB / BQ) * NSPLIT), dim3(512), 0, stream,
                     Qn, Kn, KnT, out);
}